// Round 16
// baseline (85.681 us; speedup 1.0000x reference)
//
#include <hip/hip_runtime.h>

#define PI_F 3.14159265358979323846f
#define SC (1.0f/65536.0f)

typedef unsigned u32x2 __attribute__((ext_vector_type(2)));

__device__ __forceinline__ float2 cmul(float2 a, float2 b){
  return make_float2(fmaf(a.x, b.x, -(a.y*b.y)), fmaf(a.x, b.y, a.y*b.x));
}
__device__ __forceinline__ float2 cadd(float2 a, float2 b){ return make_float2(a.x+b.x, a.y+b.y); }
__device__ __forceinline__ float2 csub(float2 a, float2 b){ return make_float2(a.x-b.x, a.y-b.y); }

__device__ __forceinline__ int rev2(int l){
  return ((l&1)<<5)|((l&2)<<3)|((l&4)<<1)|((l&8)>>1)|((l&16)>>3)|((l&32)>>5);
}

template<int SIGN>
__device__ __forceinline__ float2 twf(float th){
  float sn, cs; __sincosf(th, &sn, &cs);
  return make_float2(cs, (SIGN<0)? -sn : sn);
}

__device__ __forceinline__ unsigned short f2bf(float f){
  unsigned u = __float_as_uint(f);
  return (unsigned short)((u + 0x7FFFu + ((u >> 16) & 1u)) >> 16);
}
__device__ __forceinline__ float bf2f(unsigned short h){
  return __uint_as_float(((unsigned)h) << 16);
}

template<int CTRL>
__device__ __forceinline__ float2 dppx(float2 v){
  float2 r;
  r.x = __int_as_float(__builtin_amdgcn_update_dpp(0, __float_as_int(v.x), CTRL, 0xF, 0xF, false));
  r.y = __int_as_float(__builtin_amdgcn_update_dpp(0, __float_as_int(v.y), CTRL, 0xF, 0xF, false));
  return r;
}
template<int OFF>
__device__ __forceinline__ float2 swzx(float2 v){
  float2 r;
  r.x = __int_as_float(__builtin_amdgcn_ds_swizzle(__float_as_int(v.x), OFF));
  r.y = __int_as_float(__builtin_amdgcn_ds_swizzle(__float_as_int(v.y), OFF));
  return r;
}
__device__ __forceinline__ void x32(float2 v, int l, float2& lo, float2& hi){
#if __has_builtin(__builtin_amdgcn_permlane32_swap)
  u32x2 rx = __builtin_amdgcn_permlane32_swap(__float_as_uint(v.x), __float_as_uint(v.x), false, false);
  u32x2 ry = __builtin_amdgcn_permlane32_swap(__float_as_uint(v.y), __float_as_uint(v.y), false, false);
  lo = make_float2(__uint_as_float(rx[0]), __uint_as_float(ry[0]));
  hi = make_float2(__uint_as_float(rx[1]), __uint_as_float(ry[1]));
#else
  float2 p = make_float2(__shfl(v.x, l^32, 64), __shfl(v.y, l^32, 64));
  lo = (l&32) ? p : v;
  hi = (l&32) ? v : p;
#endif
}

template<int SIGN>
__device__ __forceinline__ void mk_tw(int l, float2 tw[5], float sg[6]){
#pragma unroll
  for(int i=0;i<6;++i){ const int m = 32>>i; sg[i] = (l&m)? -1.f : 1.f; }
#pragma unroll
  for(int i=0;i<5;++i){
    const int m = 32>>i;
    const int j = l & (m-1);
    float2 w = twf<SIGN>((2.0f*PI_F)*(float)j/(float)(2*m));
    tw[i] = (l&m) ? w : make_float2(1.f, 0.f);
  }
}

// forward 64-pt DFT across lanes (radix-2 DIF): in v[l] -> out S[rev2(l)] at lane l.
__device__ __forceinline__ float2 fladder(float2 d, int l, const float2 tw[5], const float sg[6]){
  float2 lo, hi, t, p;
  x32(d, l, lo, hi);
  t.x = fmaf(sg[0], hi.x, lo.x); t.y = fmaf(sg[0], hi.y, lo.y);
  d = cmul(t, tw[0]);
  p = swzx<0x401F>(d);
  t.x = fmaf(sg[1], d.x, p.x);  t.y = fmaf(sg[1], d.y, p.y);
  d = cmul(t, tw[1]);
  p = dppx<0x128>(d);
  t.x = fmaf(sg[2], d.x, p.x);  t.y = fmaf(sg[2], d.y, p.y);
  d = cmul(t, tw[2]);
  p = swzx<0x101F>(d);
  t.x = fmaf(sg[3], d.x, p.x);  t.y = fmaf(sg[3], d.y, p.y);
  d = cmul(t, tw[3]);
  p = dppx<0x4E>(d);
  t.x = fmaf(sg[4], d.x, p.x);  t.y = fmaf(sg[4], d.y, p.y);
  d = cmul(t, tw[4]);
  p = dppx<0xB1>(d);
  d.x = fmaf(sg[5], d.x, p.x);  d.y = fmaf(sg[5], d.y, p.y);
  return d;
}

// inverse 64-pt DFT across lanes (radix-2 DIT): in Y[rev2(l)] at lane l -> out y[l].
__device__ __forceinline__ float2 iladder(float2 d, int l, const float2 tw[5], const float sg[6]){
  float2 p, t, lo, hi;
  p = dppx<0xB1>(d);
  t.x = fmaf(sg[5], d.x, p.x);  t.y = fmaf(sg[5], d.y, p.y); d = t;
  d = cmul(d, tw[4]);
  p = dppx<0x4E>(d);
  t.x = fmaf(sg[4], d.x, p.x);  t.y = fmaf(sg[4], d.y, p.y); d = t;
  d = cmul(d, tw[3]);
  p = swzx<0x101F>(d);
  t.x = fmaf(sg[3], d.x, p.x);  t.y = fmaf(sg[3], d.y, p.y); d = t;
  d = cmul(d, tw[2]);
  p = dppx<0x128>(d);
  t.x = fmaf(sg[2], d.x, p.x);  t.y = fmaf(sg[2], d.y, p.y); d = t;
  d = cmul(d, tw[1]);
  p = swzx<0x401F>(d);
  t.x = fmaf(sg[1], d.x, p.x);  t.y = fmaf(sg[1], d.y, p.y); d = t;
  d = cmul(d, tw[0]);
  x32(d, l, lo, hi);
  d.x = fmaf(sg[0], hi.x, lo.x); d.y = fmaf(sg[0], hi.y, lo.y);
  return d;
}

// fwd3: input d[p] = x[4l+p] -> output d[k0] = X[rev2(l) + 64*k0]. Unnormalized.
__device__ __forceinline__ void fwd3(float2 d[4], int l, int r4,
                                     const float2 tw[5], const float sg[6]){
#pragma unroll
  for(int p=0;p<4;++p) d[p] = fladder(d[p], l, tw, sg);
  float2 w1 = twf<-1>((2.0f*PI_F/256.0f)*(float)r4);
  float2 w2 = cmul(w1,w1), w3 = cmul(w2,w1);
  d[1]=cmul(d[1],w1); d[2]=cmul(d[2],w2); d[3]=cmul(d[3],w3);
  float2 e=cadd(d[0],d[2]), f=csub(d[0],d[2]), g=cadd(d[1],d[3]), h=csub(d[1],d[3]);
  float2 mih = make_float2(h.y, -h.x);
  d[0]=cadd(e,g); d[1]=cadd(f,mih); d[2]=csub(e,g); d[3]=csub(f,mih);
}

// inv3: input d[k0] = Y[rev2(l) + 64*k0] -> output d[p] = z[4l+p]. Unnormalized.
__device__ __forceinline__ void inv3(float2 d[4], int l, int r4,
                                     const float2 tw[5], const float sg[6]){
  {
    float2 e=cadd(d[0],d[2]), f=csub(d[0],d[2]), g=cadd(d[1],d[3]), h=csub(d[1],d[3]);
    float2 pih = make_float2(-h.y, h.x);
    d[0]=cadd(e,g); d[1]=cadd(f,pih); d[2]=csub(e,g); d[3]=csub(f,pih);
  }
  float2 w1 = twf<1>((2.0f*PI_F/256.0f)*(float)r4);
  float2 w2 = cmul(w1,w1), w3 = cmul(w2,w1);
  d[1]=cmul(d[1],w1); d[2]=cmul(d[2],w2); d[3]=cmul(d[3],w3);
#pragma unroll
  for(int p=0;p<4;++p) d[p] = iladder(d[p], l, tw, sg);
}

// kept k = r4 + 64*k0: k0==0 kept iff r4<44 (c=r4); k0==3 kept iff r4>=19 (c=25+r4).

// K1: 256 thr, 2049 blocks. Block = 4 consecutive lines of one batch (wave = 1 line).
//     Small blocks (4 waves) instead of round-15's 1024-thr/16-wave shape: that shape
//     came out at VGPR=24 (register-starved, serial loads) and ran 41.7 us.
//     Block 2048: composite weights into wbuf (LDS-staged).
__global__ __launch_bounds__(256) void k_rowfft(const float* __restrict__ tgt,
                                                const float* __restrict__ ref,
                                                float2* __restrict__ dkwT,
                                                const float* __restrict__ w1g,
                                                const float* __restrict__ b1g,
                                                const float* __restrict__ w2g,
                                                const float* __restrict__ b2g,
                                                float* __restrict__ wbuf){
  __shared__ __align__(16) float smem[2370];   // union: cT[89][5] float2 (3560B) | wprep stage
  const int tid = threadIdx.x;
  if(blockIdx.x == 2048){
    float* w1s = smem;            // 1152
    float* w2s = smem + 1152;     // 1152
    float* b1s = smem + 2304;     // 64
    float* b2s = smem + 2368;     // 2
    for(int t = tid; t < 1152; t += 256){ w1s[t] = w1g[t]; w2s[t] = w2g[t]; }
    if(tid < 64) b1s[tid] = b1g[tid];
    if(tid >= 64 && tid < 66) b2s[tid-64] = b2g[tid-64];
    __syncthreads();
    for(int t = tid; t < 444; t += 256){
      if(t < 100){
        const int ux = t % 5, uy = (t/5) % 5, ic = (t/25) & 1, oc = t/50;
        float acc = 0.f;
        for(int mc = 0; mc < 64; ++mc)
          for(int dy = 0; dy < 3; ++dy){
            int ky = uy - dy; if((unsigned)ky >= 3u) continue;
            for(int dx = 0; dx < 3; ++dx){
              int kx = ux - dx; if((unsigned)kx >= 3u) continue;
              acc = fmaf(w2s[((oc*64+mc)*3+dy)*3+dx], w1s[((mc*2+ic)*3+ky)*3+kx], acc);
            }
          }
        wbuf[t] = acc;
      } else if(t < 102){
        const int oc = t - 100;
        float acc = b2s[oc];
        for(int mc = 0; mc < 64; ++mc){
          float s = 0.f;
          for(int d = 0; d < 9; ++d) s += w2s[(oc*64+mc)*9 + d];
          acc = fmaf(s, b1s[mc], acc);
        }
        wbuf[t] = acc;
      } else if(t < 426){
        const int g = t - 102;
        const int oc = g / 162, r1 = g - oc*162;
        const int ic = r1 / 81,  r2 = r1 - ic*81;
        const int d  = r2 / 9,   k9 = r2 - d*9;
        float acc = 0.f;
        for(int mc = 0; mc < 64; ++mc)
          acc = fmaf(w2s[(oc*64+mc)*9 + d], w1s[(mc*2+ic)*9 + k9], acc);
        wbuf[t] = acc;
      } else {
        const int i = t - 426, oc = i / 9, d = i - oc*9;
        float acc = 0.f;
        for(int mc = 0; mc < 64; ++mc)
          acc = fmaf(w2s[(oc*64+mc)*9 + d], b1s[mc], acc);
        wbuf[t] = acc;
      }
    }
    return;
  }
  float2 (*cT)[5] = reinterpret_cast<float2(*)[5]>(smem);
  const int wv = tid >> 6, ln = tid & 63, r4 = rev2(ln);
  float2 twF[5]; float sg[6];
  mk_tw<-1>(ln, twF, sg);
  const int b  = blockIdx.x >> 6;           // 0..31
  const int h0 = (blockIdx.x & 63) << 2;    // 0..252 step 4
  const int h  = h0 + wv;
  const float4 c0 = *(const float4*)(tgt + ((size_t)(b*2+0)*256 + h)*256 + 4*ln);
  const float4 c1 = *(const float4*)(tgt + ((size_t)(b*2+1)*256 + h)*256 + 4*ln);
  const float4 c2 = *(const float4*)(ref + ((size_t)(b*2+0)*256 + h)*256 + 4*ln);
  const float4 c3 = *(const float4*)(ref + ((size_t)(b*2+1)*256 + h)*256 + 4*ln);
  float2 d[4];
  d[0] = make_float2(c0.x - c2.x, c1.x - c3.x);
  d[1] = make_float2(c0.y - c2.y, c1.y - c3.y);
  d[2] = make_float2(c0.z - c2.z, c1.z - c3.z);
  d[3] = make_float2(c0.w - c2.w, c1.w - c3.w);
  fwd3(d, ln, r4, twF, sg);
  if(r4 < 44)  cT[r4][wv]      = d[0];
  if(r4 >= 19) cT[25 + r4][wv] = d[3];
  __syncthreads();
  for(int idx = tid; idx < 356; idx += 256){
    const int c = idx >> 2, hh = idx & 3;
    dkwT[(size_t)(b*89 + c)*256 + h0 + hh] = cT[c][hh];
  }
}

// K2: block = (batch, 8 columns), 512 thr (wave per column). fwd3 along h, mask, inv3.
__global__ __launch_bounds__(512) void k_colfft(const float2* __restrict__ dkwT,
                                                float2* __restrict__ dkwC){
  __shared__ __align__(16) float2 sT[8][256];
  const int tid = threadIdx.x, wv = tid >> 6, ln = tid & 63, r4 = rev2(ln);
  float2 twF[5], twI[5]; float sg[6];
  mk_tw<-1>(ln, twF, sg);
  mk_tw< 1>(ln, twI, sg);
  const int b  = blockIdx.y;
  const int c0 = blockIdx.x * 8;
  const int c  = c0 + wv;
  if(c < 89){
    const float2* src = dkwT + (size_t)(b*89 + c)*256;
    const float4* s4 = (const float4*)(src + 4*ln);
    float4 p0 = s4[0], p1 = s4[1];
    float2 d[4];
    d[0] = make_float2(p0.x, p0.y);
    d[1] = make_float2(p0.z, p0.w);
    d[2] = make_float2(p1.x, p1.y);
    d[3] = make_float2(p1.z, p1.w);
    fwd3(d, ln, r4, twF, sg);
    if(r4 >= 44) d[0] = make_float2(0.f, 0.f);
    d[1] = make_float2(0.f, 0.f);
    d[2] = make_float2(0.f, 0.f);
    if(r4 < 19) d[3] = make_float2(0.f, 0.f);
    inv3(d, ln, r4, twI, sg);
    float4* o4 = (float4*)&sT[wv][4*ln];
    o4[0] = make_float4(d[0].x, d[0].y, d[1].x, d[1].y);
    o4[1] = make_float4(d[2].x, d[2].y, d[3].x, d[3].y);
  }
  __syncthreads();
#pragma unroll
  for(int t = 0; t < 4; ++t){
    const int idx = tid + 512*t;        // 2048 = 256h x 8c
    const int hh = idx >> 3, cw = idx & 7;
    if(c0 + cw < 89)
      dkwC[((size_t)b*256 + hh)*89 + c0 + cw] = sT[cw][hh];
  }
}

// K3: wave = one image row. Row-IFFT from dkwC, +refer, write bf16 into padded
//     chg buffer [b*2+ch][260 rows][264 cols] (row r = gy+2, data at col 4+x, pads zero).
__global__ __launch_bounds__(256) void k_ifft(const float2* __restrict__ dkwC,
                                              const float* __restrict__ ref,
                                              unsigned short* __restrict__ chgb){
  const int tid = threadIdx.x, wv = tid >> 6, ln = tid & 63;
  const int w = blockIdx.x*4 + wv;          // 0..8319 = b*260 + r
  const int b = w / 260;
  const int r = w - b*260;
  const int gy = r - 2;
  unsigned short* row0 = chgb + ((size_t)(b*2 + 0)*260 + r)*264;
  unsigned short* row1 = chgb + ((size_t)(b*2 + 1)*260 + r)*264;
  const ushort4 zu = make_ushort4(0,0,0,0);
  if((unsigned)gy >= 256u){
    *(ushort4*)(row0 + 4*ln) = zu;
    *(ushort4*)(row1 + 4*ln) = zu;
    if(ln < 2){
      *(ushort4*)(row0 + 256 + 4*ln) = zu;
      *(ushort4*)(row1 + 256 + 4*ln) = zu;
    }
    return;
  }
  const int r4 = rev2(ln);
  float2 twI[5]; float sg[6];
  mk_tw<1>(ln, twI, sg);
  const float2* row = dkwC + ((size_t)b*256 + gy)*89;
  const float2 z2 = make_float2(0.f, 0.f);
  float2 d[4];
  d[0] = (r4 < 44)  ? row[r4]      : z2;
  d[1] = z2; d[2] = z2;
  d[3] = (r4 >= 19) ? row[25 + r4] : z2;
  const float4 rr = *(const float4*)(ref + ((size_t)(b*2+0)*256 + gy)*256 + 4*ln);
  const float4 ri = *(const float4*)(ref + ((size_t)(b*2+1)*256 + gy)*256 + 4*ln);
  inv3(d, ln, r4, twI, sg);
  ushort4 o0, o1;
  o0.x = f2bf(fmaf(d[0].x, SC, rr.x)); o0.y = f2bf(fmaf(d[1].x, SC, rr.y));
  o0.z = f2bf(fmaf(d[2].x, SC, rr.z)); o0.w = f2bf(fmaf(d[3].x, SC, rr.w));
  o1.x = f2bf(fmaf(d[0].y, SC, ri.x)); o1.y = f2bf(fmaf(d[1].y, SC, ri.y));
  o1.z = f2bf(fmaf(d[2].y, SC, ri.z)); o1.w = f2bf(fmaf(d[3].y, SC, ri.w));
  *(ushort4*)(row0 + 4 + 4*ln) = o0;
  *(ushort4*)(row1 + 4 + 4*ln) = o1;
  if(ln == 0){
    *(ushort4*)(row0) = zu; *(ushort4*)(row1) = zu;
  } else if(ln == 1){
    *(ushort4*)(row0 + 260) = zu; *(ushort4*)(row1 + 260) = zu;
  }
}

// K4 (LDS-tiled): block = 16x64 output tile. Stage 20x68-short window of both
// channels once into LDS, conv from LDS, G/Cb border fixup from the same tile.
__global__ __launch_bounds__(256) void k_conv(const unsigned short* __restrict__ chgb,
                                              const float* __restrict__ wb,
                                              float* __restrict__ out){
  __shared__ float wefs[102];
  __shared__ float Gs[324];
  __shared__ float Cbs[18];
  __shared__ __align__(16) unsigned short tile[2][20][72];   // 5.76 KB
  const int tid = threadIdx.x;
  const int b   = blockIdx.y;
  const int ty  = (blockIdx.x >> 2) << 4;   // output row base (0..240)
  const int tx  = (blockIdx.x & 3) << 6;    // output col base (0,64,128,192)

  for(int i = tid; i < 444; i += 256){
    float v = wb[i];
    if(i < 102) wefs[i] = v;
    else if(i < 426) Gs[i - 102] = v;
    else Cbs[i - 426] = v;
  }
  for(int idx = tid; idx < 1360; idx += 256){
    const int ch = idx / 680;
    const int rem = idx - ch*680;
    const int r  = rem / 34;
    const int c  = rem - r*34;
    const unsigned short* src = chgb + (size_t)(b*2 + ch)*260*264 + (ty + r)*264 + tx + 2 + 2*c;
    ((unsigned*)&tile[ch][r][0])[c] = *(const unsigned*)src;
  }
  __syncthreads();

  const int r0  = tid >> 4;                 // 0..15 tile row
  const int cg  = tid & 15;                 // col group
  const int lc0 = 4*cg;
  const int oy  = ty + r0;
  const int ox0 = tx + 4*cg;

  float a0[4], a1[4];
#pragma unroll
  for(int q = 0; q < 4; ++q){ a0[q] = wefs[100]; a1[q] = wefs[101]; }
#pragma unroll
  for(int uy = 0; uy < 5; ++uy){
    const unsigned* t0 = (const unsigned*)&tile[0][r0 + uy][0];
    const unsigned* t1 = (const unsigned*)&tile[1][r0 + uy][0];
    float f0[8], f1[8];
#pragma unroll
    for(int k = 0; k < 4; ++k){
      const unsigned u0 = t0[(lc0 >> 1) + k];
      const unsigned u1 = t1[(lc0 >> 1) + k];
      f0[2*k]   = __uint_as_float(u0 << 16);
      f0[2*k+1] = __uint_as_float(u0 & 0xffff0000u);
      f1[2*k]   = __uint_as_float(u1 << 16);
      f1[2*k+1] = __uint_as_float(u1 & 0xffff0000u);
    }
    const float* wa = &wefs[uy*5];
    const float* wbv= &wefs[25 + uy*5];
    const float* wc = &wefs[50 + uy*5];
    const float* wd = &wefs[75 + uy*5];
#pragma unroll
    for(int q = 0; q < 4; ++q){
#pragma unroll
      for(int u = 0; u < 5; ++u){
        a0[q] = fmaf(f0[q+u], wa[u], fmaf(f1[q+u], wbv[u], a0[q]));
        a1[q] = fmaf(f0[q+u], wc[u], fmaf(f1[q+u], wd[u], a1[q]));
      }
    }
  }

  if(oy == 0 || oy == 255 || ox0 == 0 || ox0 == 252){
#pragma unroll
    for(int q = 0; q < 4; ++q){
      const int ox = ox0 + q;
      if(oy != 0 && oy != 255 && ox != 0 && ox != 255) continue;
      for(int dy = 0; dy < 3; ++dy)
        for(int dx = 0; dx < 3; ++dx){
          const int gy2 = oy + dy - 1, gx2 = ox + dx - 1;
          if((unsigned)gy2 < 256u && (unsigned)gx2 < 256u) continue;
          const int dd = dy*3 + dx;
          float c0 = Cbs[dd], c1 = Cbs[9 + dd];
          for(int ky = 0; ky < 3; ++ky){
            const int sy = gy2 + ky - 1;
            if((unsigned)sy >= 256u) continue;
            for(int kx = 0; kx < 3; ++kx){
              const int sx = gx2 + kx - 1;
              if((unsigned)sx >= 256u) continue;
              const int k9 = ky*3 + kx;
              const float vx = bf2f(tile[0][sy + 2 - ty][sx - tx + 2]);
              const float vy = bf2f(tile[1][sy + 2 - ty][sx - tx + 2]);
              c0 += Gs[dd*9 + k9]*vx + Gs[81  + dd*9 + k9]*vy;
              c1 += Gs[162 + dd*9 + k9]*vx + Gs[243 + dd*9 + k9]*vy;
            }
          }
          a0[q] -= c0; a1[q] -= c1;
        }
    }
  }
  *(float4*)(out + ((size_t)(b*2+0)*256 + oy)*256 + ox0) = make_float4(a0[0], a0[1], a0[2], a0[3]);
  *(float4*)(out + ((size_t)(b*2+1)*256 + oy)*256 + ox0) = make_float4(a1[0], a1[1], a1[2], a1[3]);
}

extern "C" void kernel_launch(void* const* d_in, const int* in_sizes, int n_in,
                              void* d_out, int out_size, void* d_ws, size_t ws_size,
                              hipStream_t stream) {
  const float* tgt = (const float*)d_in[0];
  const float* ref = (const float*)d_in[1];
  const float* w1  = (const float*)d_in[2];
  const float* b1  = (const float*)d_in[3];
  const float* w2  = (const float*)d_in[4];
  const float* b2  = (const float*)d_in[5];
  float* out = (float*)d_out;

  // ws: dkwT @0 (5.83MB), dkwC @6MB (5.83MB), chgb @12MB (8.79MB bf16), wbuf @21MB
  float2* dkwT = (float2*)d_ws;
  float2* dkwC = (float2*)((char*)d_ws + (size_t)6*1024*1024);
  unsigned short* chgb = (unsigned short*)((char*)d_ws + (size_t)12*1024*1024);
  float* wbuf = (float*)((char*)d_ws + (size_t)21*1024*1024);

  k_rowfft<<<2049, 256, 0, stream>>>(tgt, ref, dkwT, w1, b1, w2, b2, wbuf);
  dim3 gc(12, 32);
  k_colfft<<<gc, 512, 0, stream>>>(dkwT, dkwC);
  k_ifft<<<2080, 256, 0, stream>>>(dkwC, ref, chgb);
  dim3 gv(64, 32);
  k_conv<<<gv, 256, 0, stream>>>(chgb, wbuf, out);
}

// Round 17
// 83.991 us; speedup vs baseline: 1.0201x; 1.0201x over previous
//
#include <hip/hip_runtime.h>

#define PI_F 3.14159265358979323846f
#define SC (1.0f/65536.0f)

typedef unsigned u32x2 __attribute__((ext_vector_type(2)));

__device__ __forceinline__ float2 cmul(float2 a, float2 b){
  return make_float2(fmaf(a.x, b.x, -(a.y*b.y)), fmaf(a.x, b.y, a.y*b.x));
}
__device__ __forceinline__ float2 cadd(float2 a, float2 b){ return make_float2(a.x+b.x, a.y+b.y); }
__device__ __forceinline__ float2 csub(float2 a, float2 b){ return make_float2(a.x-b.x, a.y-b.y); }

__device__ __forceinline__ int rev2(int l){
  return ((l&1)<<5)|((l&2)<<3)|((l&4)<<1)|((l&8)>>1)|((l&16)>>3)|((l&32)>>5);
}

template<int SIGN>
__device__ __forceinline__ float2 twf(float th){
  float sn, cs; __sincosf(th, &sn, &cs);
  return make_float2(cs, (SIGN<0)? -sn : sn);
}

__device__ __forceinline__ unsigned short f2bf(float f){
  unsigned u = __float_as_uint(f);
  return (unsigned short)((u + 0x7FFFu + ((u >> 16) & 1u)) >> 16);
}
__device__ __forceinline__ float bf2f(unsigned short h){
  return __uint_as_float(((unsigned)h) << 16);
}

template<int CTRL>
__device__ __forceinline__ float2 dppx(float2 v){
  float2 r;
  r.x = __int_as_float(__builtin_amdgcn_update_dpp(0, __float_as_int(v.x), CTRL, 0xF, 0xF, false));
  r.y = __int_as_float(__builtin_amdgcn_update_dpp(0, __float_as_int(v.y), CTRL, 0xF, 0xF, false));
  return r;
}
template<int OFF>
__device__ __forceinline__ float2 swzx(float2 v){
  float2 r;
  r.x = __int_as_float(__builtin_amdgcn_ds_swizzle(__float_as_int(v.x), OFF));
  r.y = __int_as_float(__builtin_amdgcn_ds_swizzle(__float_as_int(v.y), OFF));
  return r;
}
__device__ __forceinline__ void x32(float2 v, int l, float2& lo, float2& hi){
#if __has_builtin(__builtin_amdgcn_permlane32_swap)
  u32x2 rx = __builtin_amdgcn_permlane32_swap(__float_as_uint(v.x), __float_as_uint(v.x), false, false);
  u32x2 ry = __builtin_amdgcn_permlane32_swap(__float_as_uint(v.y), __float_as_uint(v.y), false, false);
  lo = make_float2(__uint_as_float(rx[0]), __uint_as_float(ry[0]));
  hi = make_float2(__uint_as_float(rx[1]), __uint_as_float(ry[1]));
#else
  float2 p = make_float2(__shfl(v.x, l^32, 64), __shfl(v.y, l^32, 64));
  lo = (l&32) ? p : v;
  hi = (l&32) ? v : p;
#endif
}

template<int SIGN>
__device__ __forceinline__ void mk_tw(int l, float2 tw[5], float sg[6]){
#pragma unroll
  for(int i=0;i<6;++i){ const int m = 32>>i; sg[i] = (l&m)? -1.f : 1.f; }
#pragma unroll
  for(int i=0;i<5;++i){
    const int m = 32>>i;
    const int j = l & (m-1);
    float2 w = twf<SIGN>((2.0f*PI_F)*(float)j/(float)(2*m));
    tw[i] = (l&m) ? w : make_float2(1.f, 0.f);
  }
}

// forward 64-pt DFT across lanes (radix-2 DIF): in v[l] -> out S[rev2(l)] at lane l.
__device__ __forceinline__ float2 fladder(float2 d, int l, const float2 tw[5], const float sg[6]){
  float2 lo, hi, t, p;
  x32(d, l, lo, hi);
  t.x = fmaf(sg[0], hi.x, lo.x); t.y = fmaf(sg[0], hi.y, lo.y);
  d = cmul(t, tw[0]);
  p = swzx<0x401F>(d);
  t.x = fmaf(sg[1], d.x, p.x);  t.y = fmaf(sg[1], d.y, p.y);
  d = cmul(t, tw[1]);
  p = dppx<0x128>(d);
  t.x = fmaf(sg[2], d.x, p.x);  t.y = fmaf(sg[2], d.y, p.y);
  d = cmul(t, tw[2]);
  p = swzx<0x101F>(d);
  t.x = fmaf(sg[3], d.x, p.x);  t.y = fmaf(sg[3], d.y, p.y);
  d = cmul(t, tw[3]);
  p = dppx<0x4E>(d);
  t.x = fmaf(sg[4], d.x, p.x);  t.y = fmaf(sg[4], d.y, p.y);
  d = cmul(t, tw[4]);
  p = dppx<0xB1>(d);
  d.x = fmaf(sg[5], d.x, p.x);  d.y = fmaf(sg[5], d.y, p.y);
  return d;
}

// inverse 64-pt DFT across lanes (radix-2 DIT): in Y[rev2(l)] at lane l -> out y[l].
__device__ __forceinline__ float2 iladder(float2 d, int l, const float2 tw[5], const float sg[6]){
  float2 p, t, lo, hi;
  p = dppx<0xB1>(d);
  t.x = fmaf(sg[5], d.x, p.x);  t.y = fmaf(sg[5], d.y, p.y); d = t;
  d = cmul(d, tw[4]);
  p = dppx<0x4E>(d);
  t.x = fmaf(sg[4], d.x, p.x);  t.y = fmaf(sg[4], d.y, p.y); d = t;
  d = cmul(d, tw[3]);
  p = swzx<0x101F>(d);
  t.x = fmaf(sg[3], d.x, p.x);  t.y = fmaf(sg[3], d.y, p.y); d = t;
  d = cmul(d, tw[2]);
  p = dppx<0x128>(d);
  t.x = fmaf(sg[2], d.x, p.x);  t.y = fmaf(sg[2], d.y, p.y); d = t;
  d = cmul(d, tw[1]);
  p = swzx<0x401F>(d);
  t.x = fmaf(sg[1], d.x, p.x);  t.y = fmaf(sg[1], d.y, p.y); d = t;
  d = cmul(d, tw[0]);
  x32(d, l, lo, hi);
  d.x = fmaf(sg[0], hi.x, lo.x); d.y = fmaf(sg[0], hi.y, lo.y);
  return d;
}

// fwd3: input d[p] = x[4l+p] -> output d[k0] = X[rev2(l) + 64*k0]. Unnormalized.
__device__ __forceinline__ void fwd3(float2 d[4], int l, int r4,
                                     const float2 tw[5], const float sg[6]){
#pragma unroll
  for(int p=0;p<4;++p) d[p] = fladder(d[p], l, tw, sg);
  float2 w1 = twf<-1>((2.0f*PI_F/256.0f)*(float)r4);
  float2 w2 = cmul(w1,w1), w3 = cmul(w2,w1);
  d[1]=cmul(d[1],w1); d[2]=cmul(d[2],w2); d[3]=cmul(d[3],w3);
  float2 e=cadd(d[0],d[2]), f=csub(d[0],d[2]), g=cadd(d[1],d[3]), h=csub(d[1],d[3]);
  float2 mih = make_float2(h.y, -h.x);
  d[0]=cadd(e,g); d[1]=cadd(f,mih); d[2]=csub(e,g); d[3]=csub(f,mih);
}

// inv3: input d[k0] = Y[rev2(l) + 64*k0] -> output d[p] = z[4l+p]. Unnormalized.
__device__ __forceinline__ void inv3(float2 d[4], int l, int r4,
                                     const float2 tw[5], const float sg[6]){
  {
    float2 e=cadd(d[0],d[2]), f=csub(d[0],d[2]), g=cadd(d[1],d[3]), h=csub(d[1],d[3]);
    float2 pih = make_float2(-h.y, h.x);
    d[0]=cadd(e,g); d[1]=cadd(f,pih); d[2]=csub(e,g); d[3]=csub(f,pih);
  }
  float2 w1 = twf<1>((2.0f*PI_F/256.0f)*(float)r4);
  float2 w2 = cmul(w1,w1), w3 = cmul(w2,w1);
  d[1]=cmul(d[1],w1); d[2]=cmul(d[2],w2); d[3]=cmul(d[3],w3);
#pragma unroll
  for(int p=0;p<4;++p) d[p] = iladder(d[p], l, tw, sg);
}

// kept k = r4 + 64*k0: k0==0 kept iff r4<44 (c=r4); k0==3 kept iff r4>=19 (c=25+r4).

// K1: 513 blocks x 256 thr. Wave = 4 lines (h = h0 + 4*wv + i); ALL 16 float4 loads
//     issued before any FFT (16KB/wave in flight — 4x round-15 MLP). Twiddles
//     amortized over 4 FFTs. cT[89][17] staging, 128B-run writes (round-10 pattern).
//     Block 512: composite weights into wbuf (LDS-staged).
__global__ __launch_bounds__(256) void k_rowfft(const float* __restrict__ tgt,
                                                const float* __restrict__ ref,
                                                float2* __restrict__ dkwT,
                                                const float* __restrict__ w1g,
                                                const float* __restrict__ b1g,
                                                const float* __restrict__ w2g,
                                                const float* __restrict__ b2g,
                                                float* __restrict__ wbuf){
  __shared__ __align__(16) float2 cT[89][17];
  const int tid = threadIdx.x;
  if(blockIdx.x == 512){
    float* wsh = (float*)cT;
    float* w1s = wsh;
    float* w2s = wsh + 1152;
    float* b1s = wsh + 2304;
    float* b2s = wsh + 2368;
    for(int t = tid; t < 1152; t += 256){ w1s[t] = w1g[t]; w2s[t] = w2g[t]; }
    if(tid < 64) b1s[tid] = b1g[tid];
    if(tid >= 64 && tid < 66) b2s[tid-64] = b2g[tid-64];
    __syncthreads();
    for(int t = tid; t < 444; t += 256){
      if(t < 100){
        const int ux = t % 5, uy = (t/5) % 5, ic = (t/25) & 1, oc = t/50;
        float acc = 0.f;
        for(int mc = 0; mc < 64; ++mc)
          for(int dy = 0; dy < 3; ++dy){
            int ky = uy - dy; if((unsigned)ky >= 3u) continue;
            for(int dx = 0; dx < 3; ++dx){
              int kx = ux - dx; if((unsigned)kx >= 3u) continue;
              acc = fmaf(w2s[((oc*64+mc)*3+dy)*3+dx], w1s[((mc*2+ic)*3+ky)*3+kx], acc);
            }
          }
        wbuf[t] = acc;
      } else if(t < 102){
        const int oc = t - 100;
        float acc = b2s[oc];
        for(int mc = 0; mc < 64; ++mc){
          float s = 0.f;
          for(int d = 0; d < 9; ++d) s += w2s[(oc*64+mc)*9 + d];
          acc = fmaf(s, b1s[mc], acc);
        }
        wbuf[t] = acc;
      } else if(t < 426){
        const int g = t - 102;
        const int oc = g / 162, r1 = g - oc*162;
        const int ic = r1 / 81,  r2 = r1 - ic*81;
        const int d  = r2 / 9,   k9 = r2 - d*9;
        float acc = 0.f;
        for(int mc = 0; mc < 64; ++mc)
          acc = fmaf(w2s[(oc*64+mc)*9 + d], w1s[(mc*2+ic)*9 + k9], acc);
        wbuf[t] = acc;
      } else {
        const int i = t - 426, oc = i / 9, d = i - oc*9;
        float acc = 0.f;
        for(int mc = 0; mc < 64; ++mc)
          acc = fmaf(w2s[(oc*64+mc)*9 + d], b1s[mc], acc);
        wbuf[t] = acc;
      }
    }
    return;
  }
  const int wv = tid >> 6, ln = tid & 63, r4 = rev2(ln);
  float2 twF[5]; float sg[6];
  mk_tw<-1>(ln, twF, sg);
  const int b  = blockIdx.x >> 4;
  const int h0 = (blockIdx.x & 15) << 4;
  const size_t pl0 = (size_t)(b*2+0)*65536, pl1 = (size_t)(b*2+1)*65536;
  const int hb = h0 + wv*4;
  // issue ALL 16 loads before any FFT work
  float4 t0[4], t1[4], r0[4], r1[4];
#pragma unroll
  for(int i = 0; i < 4; ++i){
    t0[i] = *(const float4*)(tgt + pl0 + (hb+i)*256 + 4*ln);
    t1[i] = *(const float4*)(tgt + pl1 + (hb+i)*256 + 4*ln);
    r0[i] = *(const float4*)(ref + pl0 + (hb+i)*256 + 4*ln);
    r1[i] = *(const float4*)(ref + pl1 + (hb+i)*256 + 4*ln);
  }
#pragma unroll
  for(int i = 0; i < 4; ++i){
    float2 d[4];
    d[0] = make_float2(t0[i].x - r0[i].x, t1[i].x - r1[i].x);
    d[1] = make_float2(t0[i].y - r0[i].y, t1[i].y - r1[i].y);
    d[2] = make_float2(t0[i].z - r0[i].z, t1[i].z - r1[i].z);
    d[3] = make_float2(t0[i].w - r0[i].w, t1[i].w - r1[i].w);
    fwd3(d, ln, r4, twF, sg);
    const int hh = wv*4 + i;
    if(r4 < 44)  cT[r4][hh]      = d[0];
    if(r4 >= 19) cT[25 + r4][hh] = d[3];
  }
  __syncthreads();
  for(int idx = tid; idx < 1424; idx += 256){
    const int c = idx >> 4, hh = idx & 15;
    dkwT[(size_t)(b*89 + c)*256 + h0 + hh] = cT[c][hh];
  }
}

// K2: block = (batch, 8 columns), 512 thr (wave per column). fwd3 along h, mask, inv3.
__global__ __launch_bounds__(512) void k_colfft(const float2* __restrict__ dkwT,
                                                float2* __restrict__ dkwC){
  __shared__ __align__(16) float2 sT[8][256];
  const int tid = threadIdx.x, wv = tid >> 6, ln = tid & 63, r4 = rev2(ln);
  float2 twF[5], twI[5]; float sg[6];
  mk_tw<-1>(ln, twF, sg);
  mk_tw< 1>(ln, twI, sg);
  const int b  = blockIdx.y;
  const int c0 = blockIdx.x * 8;
  const int c  = c0 + wv;
  if(c < 89){
    const float2* src = dkwT + (size_t)(b*89 + c)*256;
    const float4* s4 = (const float4*)(src + 4*ln);
    float4 p0 = s4[0], p1 = s4[1];
    float2 d[4];
    d[0] = make_float2(p0.x, p0.y);
    d[1] = make_float2(p0.z, p0.w);
    d[2] = make_float2(p1.x, p1.y);
    d[3] = make_float2(p1.z, p1.w);
    fwd3(d, ln, r4, twF, sg);
    if(r4 >= 44) d[0] = make_float2(0.f, 0.f);
    d[1] = make_float2(0.f, 0.f);
    d[2] = make_float2(0.f, 0.f);
    if(r4 < 19) d[3] = make_float2(0.f, 0.f);
    inv3(d, ln, r4, twI, sg);
    float4* o4 = (float4*)&sT[wv][4*ln];
    o4[0] = make_float4(d[0].x, d[0].y, d[1].x, d[1].y);
    o4[1] = make_float4(d[2].x, d[2].y, d[3].x, d[3].y);
  }
  __syncthreads();
#pragma unroll
  for(int t = 0; t < 4; ++t){
    const int idx = tid + 512*t;        // 2048 = 256h x 8c
    const int hh = idx >> 3, cw = idx & 7;
    if(c0 + cw < 89)
      dkwC[((size_t)b*256 + hh)*89 + c0 + cw] = sT[cw][hh];
  }
}

// K3: wave = one image row. Row-IFFT from dkwC, +refer, write bf16 into padded
//     chg buffer [b*2+ch][260 rows][264 cols] (row r = gy+2, data at col 4+x, pads zero).
__global__ __launch_bounds__(256) void k_ifft(const float2* __restrict__ dkwC,
                                              const float* __restrict__ ref,
                                              unsigned short* __restrict__ chgb){
  const int tid = threadIdx.x, wv = tid >> 6, ln = tid & 63;
  const int w = blockIdx.x*4 + wv;          // 0..8319 = b*260 + r
  const int b = w / 260;
  const int r = w - b*260;
  const int gy = r - 2;
  unsigned short* row0 = chgb + ((size_t)(b*2 + 0)*260 + r)*264;
  unsigned short* row1 = chgb + ((size_t)(b*2 + 1)*260 + r)*264;
  const ushort4 zu = make_ushort4(0,0,0,0);
  if((unsigned)gy >= 256u){
    *(ushort4*)(row0 + 4*ln) = zu;
    *(ushort4*)(row1 + 4*ln) = zu;
    if(ln < 2){
      *(ushort4*)(row0 + 256 + 4*ln) = zu;
      *(ushort4*)(row1 + 256 + 4*ln) = zu;
    }
    return;
  }
  const int r4 = rev2(ln);
  float2 twI[5]; float sg[6];
  mk_tw<1>(ln, twI, sg);
  const float2* row = dkwC + ((size_t)b*256 + gy)*89;
  const float2 z2 = make_float2(0.f, 0.f);
  float2 d[4];
  d[0] = (r4 < 44)  ? row[r4]      : z2;
  d[1] = z2; d[2] = z2;
  d[3] = (r4 >= 19) ? row[25 + r4] : z2;
  const float4 rr = *(const float4*)(ref + ((size_t)(b*2+0)*256 + gy)*256 + 4*ln);
  const float4 ri = *(const float4*)(ref + ((size_t)(b*2+1)*256 + gy)*256 + 4*ln);
  inv3(d, ln, r4, twI, sg);
  ushort4 o0, o1;
  o0.x = f2bf(fmaf(d[0].x, SC, rr.x)); o0.y = f2bf(fmaf(d[1].x, SC, rr.y));
  o0.z = f2bf(fmaf(d[2].x, SC, rr.z)); o0.w = f2bf(fmaf(d[3].x, SC, rr.w));
  o1.x = f2bf(fmaf(d[0].y, SC, ri.x)); o1.y = f2bf(fmaf(d[1].y, SC, ri.y));
  o1.z = f2bf(fmaf(d[2].y, SC, ri.z)); o1.w = f2bf(fmaf(d[3].y, SC, ri.w));
  *(ushort4*)(row0 + 4 + 4*ln) = o0;
  *(ushort4*)(row1 + 4 + 4*ln) = o1;
  if(ln == 0){
    *(ushort4*)(row0) = zu; *(ushort4*)(row1) = zu;
  } else if(ln == 1){
    *(ushort4*)(row0 + 260) = zu; *(ushort4*)(row1 + 260) = zu;
  }
}

// K4 (LDS-tiled): block = 16x64 output tile. Stage 20x68-short window of both
// channels once into LDS, conv from LDS, G/Cb border fixup from the same tile.
__global__ __launch_bounds__(256) void k_conv(const unsigned short* __restrict__ chgb,
                                              const float* __restrict__ wb,
                                              float* __restrict__ out){
  __shared__ float wefs[102];
  __shared__ float Gs[324];
  __shared__ float Cbs[18];
  __shared__ __align__(16) unsigned short tile[2][20][72];   // 5.76 KB
  const int tid = threadIdx.x;
  const int b   = blockIdx.y;
  const int ty  = (blockIdx.x >> 2) << 4;   // output row base (0..240)
  const int tx  = (blockIdx.x & 3) << 6;    // output col base (0,64,128,192)

  for(int i = tid; i < 444; i += 256){
    float v = wb[i];
    if(i < 102) wefs[i] = v;
    else if(i < 426) Gs[i - 102] = v;
    else Cbs[i - 426] = v;
  }
  for(int idx = tid; idx < 1360; idx += 256){
    const int ch = idx / 680;
    const int rem = idx - ch*680;
    const int r  = rem / 34;
    const int c  = rem - r*34;
    const unsigned short* src = chgb + (size_t)(b*2 + ch)*260*264 + (ty + r)*264 + tx + 2 + 2*c;
    ((unsigned*)&tile[ch][r][0])[c] = *(const unsigned*)src;
  }
  __syncthreads();

  const int r0  = tid >> 4;                 // 0..15 tile row
  const int cg  = tid & 15;                 // col group
  const int lc0 = 4*cg;
  const int oy  = ty + r0;
  const int ox0 = tx + 4*cg;

  float a0[4], a1[4];
#pragma unroll
  for(int q = 0; q < 4; ++q){ a0[q] = wefs[100]; a1[q] = wefs[101]; }
#pragma unroll
  for(int uy = 0; uy < 5; ++uy){
    const unsigned* t0 = (const unsigned*)&tile[0][r0 + uy][0];
    const unsigned* t1 = (const unsigned*)&tile[1][r0 + uy][0];
    float f0[8], f1[8];
#pragma unroll
    for(int k = 0; k < 4; ++k){
      const unsigned u0 = t0[(lc0 >> 1) + k];
      const unsigned u1 = t1[(lc0 >> 1) + k];
      f0[2*k]   = __uint_as_float(u0 << 16);
      f0[2*k+1] = __uint_as_float(u0 & 0xffff0000u);
      f1[2*k]   = __uint_as_float(u1 << 16);
      f1[2*k+1] = __uint_as_float(u1 & 0xffff0000u);
    }
    const float* wa = &wefs[uy*5];
    const float* wbv= &wefs[25 + uy*5];
    const float* wc = &wefs[50 + uy*5];
    const float* wd = &wefs[75 + uy*5];
#pragma unroll
    for(int q = 0; q < 4; ++q){
#pragma unroll
      for(int u = 0; u < 5; ++u){
        a0[q] = fmaf(f0[q+u], wa[u], fmaf(f1[q+u], wbv[u], a0[q]));
        a1[q] = fmaf(f0[q+u], wc[u], fmaf(f1[q+u], wd[u], a1[q]));
      }
    }
  }

  if(oy == 0 || oy == 255 || ox0 == 0 || ox0 == 252){
#pragma unroll
    for(int q = 0; q < 4; ++q){
      const int ox = ox0 + q;
      if(oy != 0 && oy != 255 && ox != 0 && ox != 255) continue;
      for(int dy = 0; dy < 3; ++dy)
        for(int dx = 0; dx < 3; ++dx){
          const int gy2 = oy + dy - 1, gx2 = ox + dx - 1;
          if((unsigned)gy2 < 256u && (unsigned)gx2 < 256u) continue;
          const int dd = dy*3 + dx;
          float c0 = Cbs[dd], c1 = Cbs[9 + dd];
          for(int ky = 0; ky < 3; ++ky){
            const int sy = gy2 + ky - 1;
            if((unsigned)sy >= 256u) continue;
            for(int kx = 0; kx < 3; ++kx){
              const int sx = gx2 + kx - 1;
              if((unsigned)sx >= 256u) continue;
              const int k9 = ky*3 + kx;
              const float vx = bf2f(tile[0][sy + 2 - ty][sx - tx + 2]);
              const float vy = bf2f(tile[1][sy + 2 - ty][sx - tx + 2]);
              c0 += Gs[dd*9 + k9]*vx + Gs[81  + dd*9 + k9]*vy;
              c1 += Gs[162 + dd*9 + k9]*vx + Gs[243 + dd*9 + k9]*vy;
            }
          }
          a0[q] -= c0; a1[q] -= c1;
        }
    }
  }
  *(float4*)(out + ((size_t)(b*2+0)*256 + oy)*256 + ox0) = make_float4(a0[0], a0[1], a0[2], a0[3]);
  *(float4*)(out + ((size_t)(b*2+1)*256 + oy)*256 + ox0) = make_float4(a1[0], a1[1], a1[2], a1[3]);
}

extern "C" void kernel_launch(void* const* d_in, const int* in_sizes, int n_in,
                              void* d_out, int out_size, void* d_ws, size_t ws_size,
                              hipStream_t stream) {
  const float* tgt = (const float*)d_in[0];
  const float* ref = (const float*)d_in[1];
  const float* w1  = (const float*)d_in[2];
  const float* b1  = (const float*)d_in[3];
  const float* w2  = (const float*)d_in[4];
  const float* b2  = (const float*)d_in[5];
  float* out = (float*)d_out;

  // ws: dkwT @0 (5.83MB), dkwC @6MB (5.83MB), chgb @12MB (8.79MB bf16), wbuf @21MB
  float2* dkwT = (float2*)d_ws;
  float2* dkwC = (float2*)((char*)d_ws + (size_t)6*1024*1024);
  unsigned short* chgb = (unsigned short*)((char*)d_ws + (size_t)12*1024*1024);
  float* wbuf = (float*)((char*)d_ws + (size_t)21*1024*1024);

  k_rowfft<<<513, 256, 0, stream>>>(tgt, ref, dkwT, w1, b1, w2, b2, wbuf);
  dim3 gc(12, 32);
  k_colfft<<<gc, 512, 0, stream>>>(dkwT, dkwC);
  k_ifft<<<2080, 256, 0, stream>>>(dkwC, ref, chgb);
  dim3 gv(64, 32);
  k_conv<<<gv, 256, 0, stream>>>(chgb, wbuf, out);
}

// Round 18
// 57.319 us; speedup vs baseline: 1.4948x; 1.4653x over previous
//
#include <hip/hip_runtime.h>

#define PI_F 3.14159265358979323846f
#define SC (1.0f/65536.0f)

typedef unsigned u32x2 __attribute__((ext_vector_type(2)));

__device__ __forceinline__ float2 cmul(float2 a, float2 b){
  return make_float2(fmaf(a.x, b.x, -(a.y*b.y)), fmaf(a.x, b.y, a.y*b.x));
}
__device__ __forceinline__ float2 cadd(float2 a, float2 b){ return make_float2(a.x+b.x, a.y+b.y); }
__device__ __forceinline__ float2 csub(float2 a, float2 b){ return make_float2(a.x-b.x, a.y-b.y); }

__device__ __forceinline__ int rev2(int l){
  return ((l&1)<<5)|((l&2)<<3)|((l&4)<<1)|((l&8)>>1)|((l&16)>>3)|((l&32)>>5);
}

template<int SIGN>
__device__ __forceinline__ float2 twf(float th){
  float sn, cs; __sincosf(th, &sn, &cs);
  return make_float2(cs, (SIGN<0)? -sn : sn);
}

__device__ __forceinline__ unsigned short f2bf(float f){
  unsigned u = __float_as_uint(f);
  return (unsigned short)((u + 0x7FFFu + ((u >> 16) & 1u)) >> 16);
}
__device__ __forceinline__ float bf2f(unsigned short h){
  return __uint_as_float(((unsigned)h) << 16);
}

template<int CTRL>
__device__ __forceinline__ float2 dppx(float2 v){
  float2 r;
  r.x = __int_as_float(__builtin_amdgcn_update_dpp(0, __float_as_int(v.x), CTRL, 0xF, 0xF, false));
  r.y = __int_as_float(__builtin_amdgcn_update_dpp(0, __float_as_int(v.y), CTRL, 0xF, 0xF, false));
  return r;
}
template<int OFF>
__device__ __forceinline__ float2 swzx(float2 v){
  float2 r;
  r.x = __int_as_float(__builtin_amdgcn_ds_swizzle(__float_as_int(v.x), OFF));
  r.y = __int_as_float(__builtin_amdgcn_ds_swizzle(__float_as_int(v.y), OFF));
  return r;
}
__device__ __forceinline__ void x32(float2 v, int l, float2& lo, float2& hi){
#if __has_builtin(__builtin_amdgcn_permlane32_swap)
  u32x2 rx = __builtin_amdgcn_permlane32_swap(__float_as_uint(v.x), __float_as_uint(v.x), false, false);
  u32x2 ry = __builtin_amdgcn_permlane32_swap(__float_as_uint(v.y), __float_as_uint(v.y), false, false);
  lo = make_float2(__uint_as_float(rx[0]), __uint_as_float(ry[0]));
  hi = make_float2(__uint_as_float(rx[1]), __uint_as_float(ry[1]));
#else
  float2 p = make_float2(__shfl(v.x, l^32, 64), __shfl(v.y, l^32, 64));
  lo = (l&32) ? p : v;
  hi = (l&32) ? v : p;
#endif
}

template<int SIGN>
__device__ __forceinline__ void mk_tw(int l, float2 tw[5], float sg[6]){
#pragma unroll
  for(int i=0;i<6;++i){ const int m = 32>>i; sg[i] = (l&m)? -1.f : 1.f; }
#pragma unroll
  for(int i=0;i<5;++i){
    const int m = 32>>i;
    const int j = l & (m-1);
    float2 w = twf<SIGN>((2.0f*PI_F)*(float)j/(float)(2*m));
    tw[i] = (l&m) ? w : make_float2(1.f, 0.f);
  }
}

// forward 64-pt DFT across lanes (radix-2 DIF): in v[l] -> out S[rev2(l)] at lane l.
__device__ __forceinline__ float2 fladder(float2 d, int l, const float2 tw[5], const float sg[6]){
  float2 lo, hi, t, p;
  x32(d, l, lo, hi);
  t.x = fmaf(sg[0], hi.x, lo.x); t.y = fmaf(sg[0], hi.y, lo.y);
  d = cmul(t, tw[0]);
  p = swzx<0x401F>(d);
  t.x = fmaf(sg[1], d.x, p.x);  t.y = fmaf(sg[1], d.y, p.y);
  d = cmul(t, tw[1]);
  p = dppx<0x128>(d);
  t.x = fmaf(sg[2], d.x, p.x);  t.y = fmaf(sg[2], d.y, p.y);
  d = cmul(t, tw[2]);
  p = swzx<0x101F>(d);
  t.x = fmaf(sg[3], d.x, p.x);  t.y = fmaf(sg[3], d.y, p.y);
  d = cmul(t, tw[3]);
  p = dppx<0x4E>(d);
  t.x = fmaf(sg[4], d.x, p.x);  t.y = fmaf(sg[4], d.y, p.y);
  d = cmul(t, tw[4]);
  p = dppx<0xB1>(d);
  d.x = fmaf(sg[5], d.x, p.x);  d.y = fmaf(sg[5], d.y, p.y);
  return d;
}

// inverse 64-pt DFT across lanes (radix-2 DIT): in Y[rev2(l)] at lane l -> out y[l].
__device__ __forceinline__ float2 iladder(float2 d, int l, const float2 tw[5], const float sg[6]){
  float2 p, t, lo, hi;
  p = dppx<0xB1>(d);
  t.x = fmaf(sg[5], d.x, p.x);  t.y = fmaf(sg[5], d.y, p.y); d = t;
  d = cmul(d, tw[4]);
  p = dppx<0x4E>(d);
  t.x = fmaf(sg[4], d.x, p.x);  t.y = fmaf(sg[4], d.y, p.y); d = t;
  d = cmul(d, tw[3]);
  p = swzx<0x101F>(d);
  t.x = fmaf(sg[3], d.x, p.x);  t.y = fmaf(sg[3], d.y, p.y); d = t;
  d = cmul(d, tw[2]);
  p = dppx<0x128>(d);
  t.x = fmaf(sg[2], d.x, p.x);  t.y = fmaf(sg[2], d.y, p.y); d = t;
  d = cmul(d, tw[1]);
  p = swzx<0x401F>(d);
  t.x = fmaf(sg[1], d.x, p.x);  t.y = fmaf(sg[1], d.y, p.y); d = t;
  d = cmul(d, tw[0]);
  x32(d, l, lo, hi);
  d.x = fmaf(sg[0], hi.x, lo.x); d.y = fmaf(sg[0], hi.y, lo.y);
  return d;
}

// fwd3: input d[p] = x[4l+p] -> output d[k0] = X[rev2(l) + 64*k0]. Unnormalized.
__device__ __forceinline__ void fwd3(float2 d[4], int l, int r4,
                                     const float2 tw[5], const float sg[6]){
#pragma unroll
  for(int p=0;p<4;++p) d[p] = fladder(d[p], l, tw, sg);
  float2 w1 = twf<-1>((2.0f*PI_F/256.0f)*(float)r4);
  float2 w2 = cmul(w1,w1), w3 = cmul(w2,w1);
  d[1]=cmul(d[1],w1); d[2]=cmul(d[2],w2); d[3]=cmul(d[3],w3);
  float2 e=cadd(d[0],d[2]), f=csub(d[0],d[2]), g=cadd(d[1],d[3]), h=csub(d[1],d[3]);
  float2 mih = make_float2(h.y, -h.x);
  d[0]=cadd(e,g); d[1]=cadd(f,mih); d[2]=csub(e,g); d[3]=csub(f,mih);
}

// inv3: input d[k0] = Y[rev2(l) + 64*k0] -> output d[p] = z[4l+p]. Unnormalized.
__device__ __forceinline__ void inv3(float2 d[4], int l, int r4,
                                     const float2 tw[5], const float sg[6]){
  {
    float2 e=cadd(d[0],d[2]), f=csub(d[0],d[2]), g=cadd(d[1],d[3]), h=csub(d[1],d[3]);
    float2 pih = make_float2(-h.y, h.x);
    d[0]=cadd(e,g); d[1]=cadd(f,pih); d[2]=csub(e,g); d[3]=csub(f,pih);
  }
  float2 w1 = twf<1>((2.0f*PI_F/256.0f)*(float)r4);
  float2 w2 = cmul(w1,w1), w3 = cmul(w2,w1);
  d[1]=cmul(d[1],w1); d[2]=cmul(d[2],w2); d[3]=cmul(d[3],w3);
#pragma unroll
  for(int p=0;p<4;++p) d[p] = iladder(d[p], l, tw, sg);
}

// kept k = r4 + 64*k0: k0==0 kept iff r4<44 (c=r4); k0==3 kept iff r4>=19 (c=25+r4).

// K1: 1024 thr, wave = one line (round-15 body). Block 512: BRANCH-FREE wprep.
// NOTE: the old wprep Weff loop had data-dependent `continue`s -> per-load waitcnt ->
// one ~40us straggler block that set this kernel's duration in rounds 10-17.
__global__ __launch_bounds__(1024) void k_rowfft(const float* __restrict__ tgt,
                                                 const float* __restrict__ ref,
                                                 float2* __restrict__ dkwT,
                                                 const float* __restrict__ w1g,
                                                 const float* __restrict__ b1g,
                                                 const float* __restrict__ w2g,
                                                 const float* __restrict__ b2g,
                                                 float* __restrict__ wbuf){
  __shared__ __align__(16) float2 cT[89][17];
  const int tid = threadIdx.x;
  if(blockIdx.x == 512){
    float* wsh = (float*)cT;
    float* w1s = wsh;            // 1152
    float* w2s = wsh + 1152;     // 1152
    float* b1s = wsh + 2304;     // 64
    float* b2s = wsh + 2368;     // 2
    for(int t = tid; t < 1152; t += 1024){ w1s[t] = w1g[t]; w2s[t] = w2g[t]; }
    if(tid < 64) b1s[tid] = b1g[tid];
    if(tid >= 64 && tid < 66) b2s[tid-64] = b2g[tid-64];
    __syncthreads();
    for(int t = tid; t < 444; t += 1024){
      if(t < 100){
        // Weff[oc][ic][uy][ux]: branch-free (predicated clamped loads, full unroll)
        const int ux = t % 5, uy = (t/5) % 5, ic = (t/25) & 1, oc = t/50;
        float acc = 0.f;
        for(int mc = 0; mc < 64; ++mc){
          const float* w2p = w2s + (oc*64 + mc)*9;
          const float* w1p = w1s + (mc*2 + ic)*9;
#pragma unroll
          for(int dy = 0; dy < 3; ++dy){
            const int ky = uy - dy;
            const bool vy = ((unsigned)ky < 3u);
#pragma unroll
            for(int dx = 0; dx < 3; ++dx){
              const int kx = ux - dx;
              const bool v = vy && ((unsigned)kx < 3u);
              const int i1 = v ? (ky*3 + kx) : 0;
              const float a = w2p[dy*3 + dx];
              const float bb = w1p[i1];
              acc = fmaf(a, v ? bb : 0.f, acc);
            }
          }
        }
        wbuf[t] = acc;
      } else if(t < 102){
        const int oc = t - 100;
        float acc = b2s[oc];
        for(int mc = 0; mc < 64; ++mc){
          const float* w2p = w2s + (oc*64 + mc)*9;
          float s = 0.f;
#pragma unroll
          for(int d = 0; d < 9; ++d) s += w2p[d];
          acc = fmaf(s, b1s[mc], acc);
        }
        wbuf[t] = acc;
      } else if(t < 426){
        const int g = t - 102;
        const int oc = g / 162, r1 = g - oc*162;
        const int ic = r1 / 81,  r2 = r1 - ic*81;
        const int d  = r2 / 9,   k9 = r2 - d*9;
        float acc = 0.f;
        for(int mc = 0; mc < 64; ++mc)
          acc = fmaf(w2s[(oc*64+mc)*9 + d], w1s[(mc*2+ic)*9 + k9], acc);
        wbuf[t] = acc;
      } else {
        const int i = t - 426, oc = i / 9, d = i - oc*9;
        float acc = 0.f;
        for(int mc = 0; mc < 64; ++mc)
          acc = fmaf(w2s[(oc*64+mc)*9 + d], b1s[mc], acc);
        wbuf[t] = acc;
      }
    }
    return;
  }
  const int wv = tid >> 6, ln = tid & 63, r4 = rev2(ln);
  float2 twF[5]; float sg[6];
  mk_tw<-1>(ln, twF, sg);
  const int b  = blockIdx.x >> 4;
  const int h0 = (blockIdx.x & 15) << 4;
  const int h  = h0 + wv;
  const float4 c0 = *(const float4*)(tgt + ((size_t)(b*2+0)*256 + h)*256 + 4*ln);
  const float4 c1 = *(const float4*)(tgt + ((size_t)(b*2+1)*256 + h)*256 + 4*ln);
  const float4 c2 = *(const float4*)(ref + ((size_t)(b*2+0)*256 + h)*256 + 4*ln);
  const float4 c3 = *(const float4*)(ref + ((size_t)(b*2+1)*256 + h)*256 + 4*ln);
  float2 d[4];
  d[0] = make_float2(c0.x - c2.x, c1.x - c3.x);
  d[1] = make_float2(c0.y - c2.y, c1.y - c3.y);
  d[2] = make_float2(c0.z - c2.z, c1.z - c3.z);
  d[3] = make_float2(c0.w - c2.w, c1.w - c3.w);
  fwd3(d, ln, r4, twF, sg);
  if(r4 < 44)  cT[r4][wv]      = d[0];
  if(r4 >= 19) cT[25 + r4][wv] = d[3];
  __syncthreads();
  for(int idx = tid; idx < 1424; idx += 1024){
    const int c = idx >> 4, hh = idx & 15;
    dkwT[(size_t)(b*89 + c)*256 + h0 + hh] = cT[c][hh];
  }
}

// K2: block = (batch, 8 columns), 512 thr (wave per column). fwd3 along h, mask, inv3.
__global__ __launch_bounds__(512) void k_colfft(const float2* __restrict__ dkwT,
                                                float2* __restrict__ dkwC){
  __shared__ __align__(16) float2 sT[8][256];
  const int tid = threadIdx.x, wv = tid >> 6, ln = tid & 63, r4 = rev2(ln);
  float2 twF[5], twI[5]; float sg[6];
  mk_tw<-1>(ln, twF, sg);
  mk_tw< 1>(ln, twI, sg);
  const int b  = blockIdx.y;
  const int c0 = blockIdx.x * 8;
  const int c  = c0 + wv;
  if(c < 89){
    const float2* src = dkwT + (size_t)(b*89 + c)*256;
    const float4* s4 = (const float4*)(src + 4*ln);
    float4 p0 = s4[0], p1 = s4[1];
    float2 d[4];
    d[0] = make_float2(p0.x, p0.y);
    d[1] = make_float2(p0.z, p0.w);
    d[2] = make_float2(p1.x, p1.y);
    d[3] = make_float2(p1.z, p1.w);
    fwd3(d, ln, r4, twF, sg);
    if(r4 >= 44) d[0] = make_float2(0.f, 0.f);
    d[1] = make_float2(0.f, 0.f);
    d[2] = make_float2(0.f, 0.f);
    if(r4 < 19) d[3] = make_float2(0.f, 0.f);
    inv3(d, ln, r4, twI, sg);
    float4* o4 = (float4*)&sT[wv][4*ln];
    o4[0] = make_float4(d[0].x, d[0].y, d[1].x, d[1].y);
    o4[1] = make_float4(d[2].x, d[2].y, d[3].x, d[3].y);
  }
  __syncthreads();
#pragma unroll
  for(int t = 0; t < 4; ++t){
    const int idx = tid + 512*t;        // 2048 = 256h x 8c
    const int hh = idx >> 3, cw = idx & 7;
    if(c0 + cw < 89)
      dkwC[((size_t)b*256 + hh)*89 + c0 + cw] = sT[cw][hh];
  }
}

// K3: wave = one image row. Row-IFFT from dkwC, +refer, write bf16 into padded
//     chg buffer [b*2+ch][260 rows][264 cols] (row r = gy+2, data at col 4+x, pads zero).
__global__ __launch_bounds__(256) void k_ifft(const float2* __restrict__ dkwC,
                                              const float* __restrict__ ref,
                                              unsigned short* __restrict__ chgb){
  const int tid = threadIdx.x, wv = tid >> 6, ln = tid & 63;
  const int w = blockIdx.x*4 + wv;          // 0..8319 = b*260 + r
  const int b = w / 260;
  const int r = w - b*260;
  const int gy = r - 2;
  unsigned short* row0 = chgb + ((size_t)(b*2 + 0)*260 + r)*264;
  unsigned short* row1 = chgb + ((size_t)(b*2 + 1)*260 + r)*264;
  const ushort4 zu = make_ushort4(0,0,0,0);
  if((unsigned)gy >= 256u){
    *(ushort4*)(row0 + 4*ln) = zu;
    *(ushort4*)(row1 + 4*ln) = zu;
    if(ln < 2){
      *(ushort4*)(row0 + 256 + 4*ln) = zu;
      *(ushort4*)(row1 + 256 + 4*ln) = zu;
    }
    return;
  }
  const int r4 = rev2(ln);
  float2 twI[5]; float sg[6];
  mk_tw<1>(ln, twI, sg);
  const float2* row = dkwC + ((size_t)b*256 + gy)*89;
  const float2 z2 = make_float2(0.f, 0.f);
  float2 d[4];
  d[0] = (r4 < 44)  ? row[r4]      : z2;
  d[1] = z2; d[2] = z2;
  d[3] = (r4 >= 19) ? row[25 + r4] : z2;
  const float4 rr = *(const float4*)(ref + ((size_t)(b*2+0)*256 + gy)*256 + 4*ln);
  const float4 ri = *(const float4*)(ref + ((size_t)(b*2+1)*256 + gy)*256 + 4*ln);
  inv3(d, ln, r4, twI, sg);
  ushort4 o0, o1;
  o0.x = f2bf(fmaf(d[0].x, SC, rr.x)); o0.y = f2bf(fmaf(d[1].x, SC, rr.y));
  o0.z = f2bf(fmaf(d[2].x, SC, rr.z)); o0.w = f2bf(fmaf(d[3].x, SC, rr.w));
  o1.x = f2bf(fmaf(d[0].y, SC, ri.x)); o1.y = f2bf(fmaf(d[1].y, SC, ri.y));
  o1.z = f2bf(fmaf(d[2].y, SC, ri.z)); o1.w = f2bf(fmaf(d[3].y, SC, ri.w));
  *(ushort4*)(row0 + 4 + 4*ln) = o0;
  *(ushort4*)(row1 + 4 + 4*ln) = o1;
  if(ln == 0){
    *(ushort4*)(row0) = zu; *(ushort4*)(row1) = zu;
  } else if(ln == 1){
    *(ushort4*)(row0 + 260) = zu; *(ushort4*)(row1 + 260) = zu;
  }
}

// K4 (LDS-tiled): block = 16x64 output tile. Stage 20x68-short window of both
// channels once into LDS, conv from LDS, G/Cb border fixup from the same tile.
__global__ __launch_bounds__(256) void k_conv(const unsigned short* __restrict__ chgb,
                                              const float* __restrict__ wb,
                                              float* __restrict__ out){
  __shared__ float wefs[102];
  __shared__ float Gs[324];
  __shared__ float Cbs[18];
  __shared__ __align__(16) unsigned short tile[2][20][72];   // 5.76 KB
  const int tid = threadIdx.x;
  const int b   = blockIdx.y;
  const int ty  = (blockIdx.x >> 2) << 4;   // output row base (0..240)
  const int tx  = (blockIdx.x & 3) << 6;    // output col base (0,64,128,192)

  for(int i = tid; i < 444; i += 256){
    float v = wb[i];
    if(i < 102) wefs[i] = v;
    else if(i < 426) Gs[i - 102] = v;
    else Cbs[i - 426] = v;
  }
  for(int idx = tid; idx < 1360; idx += 256){
    const int ch = idx / 680;
    const int rem = idx - ch*680;
    const int r  = rem / 34;
    const int c  = rem - r*34;
    const unsigned short* src = chgb + (size_t)(b*2 + ch)*260*264 + (ty + r)*264 + tx + 2 + 2*c;
    ((unsigned*)&tile[ch][r][0])[c] = *(const unsigned*)src;
  }
  __syncthreads();

  const int r0  = tid >> 4;                 // 0..15 tile row
  const int cg  = tid & 15;                 // col group
  const int lc0 = 4*cg;
  const int oy  = ty + r0;
  const int ox0 = tx + 4*cg;

  float a0[4], a1[4];
#pragma unroll
  for(int q = 0; q < 4; ++q){ a0[q] = wefs[100]; a1[q] = wefs[101]; }
#pragma unroll
  for(int uy = 0; uy < 5; ++uy){
    const unsigned* t0 = (const unsigned*)&tile[0][r0 + uy][0];
    const unsigned* t1 = (const unsigned*)&tile[1][r0 + uy][0];
    float f0[8], f1[8];
#pragma unroll
    for(int k = 0; k < 4; ++k){
      const unsigned u0 = t0[(lc0 >> 1) + k];
      const unsigned u1 = t1[(lc0 >> 1) + k];
      f0[2*k]   = __uint_as_float(u0 << 16);
      f0[2*k+1] = __uint_as_float(u0 & 0xffff0000u);
      f1[2*k]   = __uint_as_float(u1 << 16);
      f1[2*k+1] = __uint_as_float(u1 & 0xffff0000u);
    }
    const float* wa = &wefs[uy*5];
    const float* wbv= &wefs[25 + uy*5];
    const float* wc = &wefs[50 + uy*5];
    const float* wd = &wefs[75 + uy*5];
#pragma unroll
    for(int q = 0; q < 4; ++q){
#pragma unroll
      for(int u = 0; u < 5; ++u){
        a0[q] = fmaf(f0[q+u], wa[u], fmaf(f1[q+u], wbv[u], a0[q]));
        a1[q] = fmaf(f0[q+u], wc[u], fmaf(f1[q+u], wd[u], a1[q]));
      }
    }
  }

  if(oy == 0 || oy == 255 || ox0 == 0 || ox0 == 252){
#pragma unroll
    for(int q = 0; q < 4; ++q){
      const int ox = ox0 + q;
      if(oy != 0 && oy != 255 && ox != 0 && ox != 255) continue;
      for(int dy = 0; dy < 3; ++dy)
        for(int dx = 0; dx < 3; ++dx){
          const int gy2 = oy + dy - 1, gx2 = ox + dx - 1;
          if((unsigned)gy2 < 256u && (unsigned)gx2 < 256u) continue;
          const int dd = dy*3 + dx;
          float c0 = Cbs[dd], c1 = Cbs[9 + dd];
          for(int ky = 0; ky < 3; ++ky){
            const int sy = gy2 + ky - 1;
            if((unsigned)sy >= 256u) continue;
            for(int kx = 0; kx < 3; ++kx){
              const int sx = gx2 + kx - 1;
              if((unsigned)sx >= 256u) continue;
              const int k9 = ky*3 + kx;
              const float vx = bf2f(tile[0][sy + 2 - ty][sx - tx + 2]);
              const float vy = bf2f(tile[1][sy + 2 - ty][sx - tx + 2]);
              c0 += Gs[dd*9 + k9]*vx + Gs[81  + dd*9 + k9]*vy;
              c1 += Gs[162 + dd*9 + k9]*vx + Gs[243 + dd*9 + k9]*vy;
            }
          }
          a0[q] -= c0; a1[q] -= c1;
        }
    }
  }
  *(float4*)(out + ((size_t)(b*2+0)*256 + oy)*256 + ox0) = make_float4(a0[0], a0[1], a0[2], a0[3]);
  *(float4*)(out + ((size_t)(b*2+1)*256 + oy)*256 + ox0) = make_float4(a1[0], a1[1], a1[2], a1[3]);
}

extern "C" void kernel_launch(void* const* d_in, const int* in_sizes, int n_in,
                              void* d_out, int out_size, void* d_ws, size_t ws_size,
                              hipStream_t stream) {
  const float* tgt = (const float*)d_in[0];
  const float* ref = (const float*)d_in[1];
  const float* w1  = (const float*)d_in[2];
  const float* b1  = (const float*)d_in[3];
  const float* w2  = (const float*)d_in[4];
  const float* b2  = (const float*)d_in[5];
  float* out = (float*)d_out;

  // ws: dkwT @0 (5.83MB), dkwC @6MB (5.83MB), chgb @12MB (8.79MB bf16), wbuf @21MB
  float2* dkwT = (float2*)d_ws;
  float2* dkwC = (float2*)((char*)d_ws + (size_t)6*1024*1024);
  unsigned short* chgb = (unsigned short*)((char*)d_ws + (size_t)12*1024*1024);
  float* wbuf = (float*)((char*)d_ws + (size_t)21*1024*1024);

  k_rowfft<<<513, 1024, 0, stream>>>(tgt, ref, dkwT, w1, b1, w2, b2, wbuf);
  dim3 gc(12, 32);
  k_colfft<<<gc, 512, 0, stream>>>(dkwT, dkwC);
  k_ifft<<<2080, 256, 0, stream>>>(dkwC, ref, chgb);
  dim3 gv(64, 32);
  k_conv<<<gv, 256, 0, stream>>>(chgb, wbuf, out);
}